// Round 6
// baseline (1055.047 us; speedup 1.0000x reference)
//
#include <hip/hip_runtime.h>
#include <hip/hip_bf16.h>

// MambaSSMBlock: HID=1024, STATE=16, K=4, EXPAND=2, INNER=2048, B=4, L=4096
#define HID   1024
#define STATE 16
#define KCONV 4
#define INNER 2048
#define BSZ   4
#define LSEQ  4096
#define BL    (BSZ * LSEQ)       // 16384 rows
#define NCAT  2176               // 2048 (dt) + 16 (B) + 16 (C) + 96 pad -> 17 tiles of 128
#define NCH   64                 // scan chunks
#define TC    64                 // steps per chunk (NCH*TC == LSEQ)

typedef unsigned short ushort_t;
typedef unsigned int   uint_t;
typedef __attribute__((ext_vector_type(8))) __bf16 bf16x8;
typedef __attribute__((ext_vector_type(4))) float  f32x4;
typedef __attribute__((ext_vector_type(8))) unsigned short u16x8;

// ---------- helpers ----------
__device__ __forceinline__ ushort_t f2bf(float f) {
    uint_t u = __float_as_uint(f);
    u += 0x7fffu + ((u >> 16) & 1u);       // RNE (finite values only here)
    return (ushort_t)(u >> 16);
}
__device__ __forceinline__ float bf2f(ushort_t h) {
    return __uint_as_float(((uint_t)h) << 16);
}

#define AS1 __attribute__((address_space(1)))
#define AS3 __attribute__((address_space(3)))
__device__ __forceinline__ void async_copy16(const ushort_t* g, ushort_t* l) {
    // LDS dest is wave-uniform base; HW writes lane i at base + i*16B
    __builtin_amdgcn_global_load_lds((const AS1 void*)g, (AS3 void*)l, 16, 0, 0);
}

// ---------- elementwise cast ----------
__global__ void cast_bf16_kernel(const float* __restrict__ src, ushort_t* __restrict__ dst, int n) {
    int i = blockIdx.x * 256 + threadIdx.x;
    if (i < n) dst[i] = f2bf(src[i]);
}

// ---------- build concatenated [dt_w; B_w; C_w; 0-pad] bf16 weight (NCAT x 2048) ----------
__global__ void build_wcat_kernel(const float* __restrict__ dtw, const float* __restrict__ Bw,
                                  const float* __restrict__ Cw, ushort_t* __restrict__ out) {
    int i = blockIdx.x * 256 + threadIdx.x;
    if (i >= NCAT * INNER) return;
    int r = i >> 11;           // / 2048
    int k = i & (INNER - 1);
    float v = 0.f;
    if (r < INNER)            v = dtw[i];
    else if (r < INNER + 16)  v = Bw[(r - INNER) * INNER + k];
    else if (r < INNER + 32)  v = Cw[(r - INNER - 16) * INNER + k];
    out[i] = f2bf(v);
}

__global__ void build_biascat_kernel(const float* __restrict__ dtb, const float* __restrict__ Bb,
                                     const float* __restrict__ Cb, float* __restrict__ out) {
    int i = blockIdx.x * 256 + threadIdx.x;
    if (i >= NCAT) return;
    float v = 0.f;
    if (i < INNER)            v = dtb[i];
    else if (i < INNER + 16)  v = Bb[i - INNER];
    else if (i < INNER + 32)  v = Cb[i - INNER - 16];
    out[i] = v;
}

// ---------- 256x128x64 2-phase bf16 MFMA GEMM: C = A(M,K) @ B(N,K)^T ----------
// T3-minimal 2-phase (catalog: 2ph-256sq = 655-682 TF, m230/m248): per K-tile
// {STAGE(t+1) -> ds_read+MFMA(t) -> vmcnt(0) -> barrier}. Stage is issued
// BEFORE compute so HBM latency hides under ~2000cy of MFMA; single barrier
// per tile. No setprio (T5 null at 2ph), no cross-phase register holds.
// BN=128 -> acc[8][2] = 64 f32/lane: total ~120 regs, far below the 256 cap.
// (R3/R5 8-phase at 256x256 had acc=128 + cross-phase holds -> the allocator
// spilled the accumulator to scratch: WRITE_SIZE 362MB vs 128MB ideal, i.e.
// +512B/thread = exactly acc. This 2ph config removes the pressure.)
// LDS: 2 bufs x [B(128x64)|A0|A1] x 16KB = 96KB. T2 XOR swizzle kept
// (R3-verified: SQ_LDS_BANK_CONFLICT == 0): source chunk pre-swizzled
// c16^(row&7), same XOR on ds_read. T1 XCD banding kept.
// MODE 0: in_proj  -> col<2048: x_part bf16; col>=2048: silu(z) bf16
// MODE 1: dt/Bm/Cm -> col<2048: softplus->dt bf16; [2048,2064): Bm; [2064,2080): Cm; pad dropped
// MODE 2: out_proj -> bias add, fp32
#define mfma_bf16 __builtin_amdgcn_mfma_f32_16x16x32_bf16

template <int MODE, int KK>
__global__ __launch_bounds__(512, 2) void gemm256_kernel(
    const ushort_t* __restrict__ A, const ushort_t* __restrict__ Bw,
    const float* __restrict__ bias,
    ushort_t* __restrict__ oU0, ushort_t* __restrict__ oU1,
    float* __restrict__ oF, float* __restrict__ oB, float* __restrict__ oC,
    int N)
{
    __shared__ ushort_t smem[49152];   // 96 KiB: 2 bufs x 3 slots x 8192 ushorts

    const int tid  = threadIdx.x;
    const int w    = tid >> 6;
    const int lane = tid & 63;
    const int m16  = lane & 15;
    const int ko   = lane >> 4;        // 0..3 : which 8-elem k-chunk
    const int wm   = w >> 2;           // 0..1 : row-half of the 256-row tile
    const int wn   = w & 3;            // 0..3 : 32-col quarter of the 128-col tile

    // ----- XCD-banded swizzle (gridDim.y == 64, nwg % 8 == 0 for all shapes) -----
    const int gx   = gridDim.x;
    const int lb   = blockIdx.y * gx + blockIdx.x;
    const int xcd  = lb & 7;
    const int slot = lb >> 3;
    const int tx   = slot % gx;
    const int ty   = xcd * 8 + slot / gx;    // 8 row-tiles per XCD band
    const int row0 = ty * 256;
    const int col0 = tx * 128;

    constexpr int NKT = KK >> 6;       // K-tiles of 64

    // per-lane staging base (swizzle pre-applied to GLOBAL source; LDS dest
    // linear -- rule #21): lane covers row w*16 + i*8 + (lane>>3), chunk
    // c16 = lane&7, src chunk = c16 ^ (row&7) = (lane&7)^(lane>>3).
    const size_t Lofs = (size_t)(w * 16 + (lane >> 3)) * KK
                      + (size_t)(((lane & 7) ^ (lane >> 3)) << 3);
    const ushort_t* pA = A  + (size_t)row0 * KK + Lofs;
    const ushort_t* pB = Bw + (size_t)col0 * KK + Lofs;

    f32x4 acc[8][2] = {};

    // stage K-tile tau into buffer (tau&1): slots j=0:B(128r), j=1:A rows 0-127,
    // j=2:A rows 128-255. 2 copies per wave per slot (1KB each).
    auto stage_tile = [&](int tau) {
        const int bb = (tau & 1) * 24576;
        const int k0 = tau << 6;
#pragma unroll
        for (int j = 0; j < 3; j++) {
            const ushort_t* px = (j == 0) ? pB : pA + (size_t)((j - 1) << 7) * KK;
#pragma unroll
            for (int i = 0; i < 2; i++) {
                const ushort_t* s = px + (size_t)(i * 8) * KK + k0;
                async_copy16(s, &smem[bb + j * 8192 + w * 1024 + i * 512]);
            }
        }
    };
    // swizzled ds_read of one bf16x8 MFMA fragment (row stride 64 ushorts=128B)
    auto ldA = [&](int buf, int rf, int s) -> bf16x8 {
        const int row = (rf << 4) + m16;                 // within wm's 128-row half
        const int c16 = ((s << 2) + ko) ^ (row & 7);
        return *(const bf16x8*)&smem[buf * 24576 + (1 + wm) * 8192 + (row << 6) + (c16 << 3)];
    };
    auto ldB = [&](int buf, int cf, int s) -> bf16x8 {
        const int row = (wn << 5) + (cf << 4) + m16;     // 0..127
        const int c16 = ((s << 2) + ko) ^ (row & 7);
        return *(const bf16x8*)&smem[buf * 24576 + (row << 6) + (c16 << 3)];
    };

    // prologue: stage tile 0, drain, barrier
    stage_tile(0);
    asm volatile("s_waitcnt vmcnt(0)" ::: "memory");
    __builtin_amdgcn_s_barrier();

#pragma unroll 1
    for (int t = 0; t < NKT; ++t) {
        const int buf = t & 1;
        if (t + 1 < NKT) stage_tile(t + 1);      // into buf^1; latency hides under MFMA

#pragma unroll
        for (int s = 0; s < 2; s++) {
            const bf16x8 b0 = ldB(buf, 0, s);
            const bf16x8 b1 = ldB(buf, 1, s);
#pragma unroll
            for (int rf = 0; rf < 8; rf++) {
                const bf16x8 a = ldA(buf, rf, s);
                acc[rf][0] = mfma_bf16(a, b0, acc[rf][0], 0, 0, 0);
                acc[rf][1] = mfma_bf16(a, b1, acc[rf][1], 0, 0, 0);
            }
        }
        if (t + 1 < NKT) {
            asm volatile("s_waitcnt vmcnt(0)" ::: "memory");   // next tile resident
            __builtin_amdgcn_s_barrier();                      // + all reads of buf done
        }
    }

    // ---------------- epilogue ----------------
    // C/D layout: col = lane&15, row = (lane>>4)*4 + reg
    const int rbase = (lane >> 4) * 4;
    __syncthreads();   // all K-loop LDS reads done before smem reuse; drains cnts

    if (MODE == 2) {
        // fp32 direct: 16 lanes x 4B contiguous = full 64B line per store instr
#pragma unroll
        for (int rf = 0; rf < 8; rf++)
#pragma unroll
            for (int cf = 0; cf < 2; cf++)
#pragma unroll
                for (int r = 0; r < 4; r++) {
                    int row = row0 + wm * 128 + rf * 16 + rbase + r;
                    int col = col0 + wn * 32 + cf * 16 + m16;
                    oF[(size_t)row * N + col] = acc[rf][cf][r] + bias[col];
                }
    } else if (MODE == 1 && col0 >= INNER) {
        // Bm/Cm strip (cols 2048..2079) + pad cols: scalar fp32, tiny
#pragma unroll
        for (int rf = 0; rf < 8; rf++)
#pragma unroll
            for (int cf = 0; cf < 2; cf++)
#pragma unroll
                for (int r = 0; r < 4; r++) {
                    int row = row0 + wm * 128 + rf * 16 + rbase + r;
                    int col = col0 + wn * 32 + cf * 16 + m16;
                    float v = acc[rf][cf][r] + bias[col];
                    if (col < INNER + 16)      oB[(size_t)row * STATE + (col - INNER)] = v;
                    else if (col < INNER + 32) oC[(size_t)row * STATE + (col - INNER - 16)] = v;
                }
    } else {
        // bf16 modes: per-wave-private LDS transpose -> u16x8 full-line stores
        const bool isZ = (MODE == 0) && (col0 >= INNER);   // block-uniform
        ushort_t* my = &smem[w * 4608];                    // 128 rows x 36 ushorts
        const int SW = 36;                                 // padded row stride
#pragma unroll
        for (int rf = 0; rf < 8; rf++)
#pragma unroll
            for (int cf = 0; cf < 2; cf++)
#pragma unroll
                for (int r = 0; r < 4; r++) {
                    int lr = rf * 16 + rbase + r;          // 0..127
                    int lc = cf * 16 + m16;                // 0..31
                    float v = acc[rf][cf][r] + bias[col0 + wn * 32 + lc];
                    ushort_t o;
                    if (MODE == 0) {
                        if (isZ) { float s = v / (1.f + __expf(-v)); o = f2bf(s); }
                        else     { o = f2bf(v); }
                    } else {
                        float sp = fmaxf(v, 0.f) + log1pf(__expf(-fabsf(v)));
                        o = f2bf(sp);
                    }
                    my[lr * SW + lc] = o;
                }
        // same-wave DS ordering (HW in-order per wave); sched_barrier as
        // insurance against compile-time reordering of the read loop
        __builtin_amdgcn_sched_barrier(0);
#pragma unroll
        for (int it = 0; it < 8; it++) {
            int lr = it * 16 + (lane >> 2);                // 0..127
            u16x8 vv = *(const u16x8*)&my[lr * SW + (lane & 3) * 8];
            int grow = row0 + wm * 128 + lr;
            int gcol = col0 + wn * 32 + (lane & 3) * 8;
            if (MODE == 0 && isZ)
                *(u16x8*)&oU1[(size_t)grow * INNER + (gcol - INNER)] = vv;
            else
                *(u16x8*)&oU0[(size_t)grow * INNER + gcol] = vv;
        }
    }
}

// ---------- causal depthwise conv (K=4) + silu; bf16 in, bf16 out ----------
// Vectorized x8 (G13): each thread owns 8 contiguous channels at one (b,l);
// u16x8 loads for the 4 tap rows, conv weights hoisted to registers.
__global__ void conv_silu_kernel(const ushort_t* __restrict__ xp, const float* __restrict__ cw,
                                 const float* __restrict__ cb,
                                 ushort_t* __restrict__ xcbf) {
    int i = blockIdx.x * 256 + threadIdx.x;     // over BL*INNER/8
    int base = i * 8;
    int d0 = base & (INNER - 1);
    int bl = base >> 11;
    int l  = bl & (LSEQ - 1);

    f32x4 wv[8];
    float acc[8];
#pragma unroll
    for (int j = 0; j < 8; j++) {
        wv[j]  = *(const f32x4*)&cw[(d0 + j) * KCONV];
        acc[j] = cb[d0 + j];
    }
#pragma unroll
    for (int k = 0; k < KCONV; k++) {
        int ls = l - (KCONV - 1) + k;
        if (ls >= 0) {
            u16x8 v = *(const u16x8*)&xp[base + (ls - l) * INNER];
#pragma unroll
            for (int j = 0; j < 8; j++) acc[j] = fmaf(wv[j][k], bf2f(v[j]), acc[j]);
        }
    }
    u16x8 o;
#pragma unroll
    for (int j = 0; j < 8; j++) {
        float s = acc[j] / (1.f + __expf(-acc[j]));
        o[j] = f2bf(s);
    }
    *(u16x8*)&xcbf[base] = o;
}

// ---------- chunked parallel scan, thread-per-channel ----------
__global__ __launch_bounds__(256) void scan_pass1(
    const ushort_t* __restrict__ dt, const ushort_t* __restrict__ xc,
    const float* __restrict__ Bm, const float* __restrict__ A_log,
    ushort_t* __restrict__ Pc, float* __restrict__ Sc)
{
    const int b = blockIdx.z;
    const int c = blockIdx.y;
    const int d = blockIdx.x * 256 + threadIdx.x;

    float A[STATE], h[STATE];
    {
        float al[STATE];
#pragma unroll
        for (int q = 0; q < 4; q++)
            *(f32x4*)(al + q * 4) = *(const f32x4*)(A_log + (size_t)d * STATE + q * 4);
#pragma unroll
        for (int s = 0; s < STATE; s++) { A[s] = -__expf(al[s]); h[s] = 0.f; }
    }
    float sdt = 0.f;
    const size_t base = (size_t)b * LSEQ + (size_t)c * TC;

#pragma unroll 2
    for (int t = 0; t < TC; t++) {
        const size_t r = base + t;
        const float dtv = bf2f(dt[r * INNER + d]);
        const float xv  = bf2f(xc[r * INNER + d]);
        const float dtx = dtv * xv;
        float Bv[STATE];
#pragma unroll
        for (int q = 0; q < 4; q++)
            *(f32x4*)(Bv + q * 4) = *(const f32x4*)(Bm + r * STATE + q * 4);
        sdt += dtv;
#pragma unroll
        for (int s = 0; s < STATE; s++) {
            const float dA = __expf(dtv * A[s]);
            h[s] = fmaf(dA, h[s], dtx * Bv[s]);
        }
    }

    const size_t idx = ((size_t)(b * NCH + c) * INNER + d) * STATE;
#pragma unroll
    for (int q = 0; q < 4; q++)
        *(f32x4*)(Sc + idx + q * 4) = *(const f32x4*)(h + q * 4);
    u16x8 p0, p1;
#pragma unroll
    for (int s = 0; s < 8; s++) { p0[s] = f2bf(__expf(A[s] * sdt)); }
#pragma unroll
    for (int s = 0; s < 8; s++) { p1[s] = f2bf(__expf(A[s + 8] * sdt)); }
    *(u16x8*)(Pc + idx)     = p0;
    *(u16x8*)(Pc + idx + 8) = p1;
}

// Pass 2: exclusive scan over chunks (in-place: S becomes H = chunk-initial state).
__global__ __launch_bounds__(256) void scan_pass2(
    const ushort_t* __restrict__ Pc, float* Sc)
{
    const int i = blockIdx.x * 256 + threadIdx.x;      // over BSZ*INNER*STATE
    const int b   = i >> 15;                           // / (INNER*STATE)
    const int rem = i & (INNER * STATE - 1);
    float H = 0.f;
#pragma unroll 8
    for (int c = 0; c < NCH; c++) {
        const size_t idx = (size_t)(b * NCH + c) * (INNER * STATE) + rem;
        const float Pv = bf2f(Pc[idx]);
        const float Sv = Sc[idx];
        const float Hn = fmaf(Pv, H, Sv);
        Sc[idx] = H;                                   // exclusive: h at chunk start
        H = Hn;
    }
}

// Pass 3: re-run local scan seeded with H; y = sum_s h[s]*C[s] + D*x; gate with
// silu(z) in-place. No shuffles: states are registers.
__global__ __launch_bounds__(256) void scan_pass3(
    const ushort_t* __restrict__ dt, const ushort_t* __restrict__ xc,
    const float* __restrict__ Bm, const float* __restrict__ Cm,
    const float* __restrict__ A_log, const float* __restrict__ Dv,
    const float* __restrict__ Hc, ushort_t* sz_y)
{
    const int b = blockIdx.z;
    const int c = blockIdx.y;
    const int d = blockIdx.x * 256 + threadIdx.x;

    float A[STATE], h[STATE];
    {
        float al[STATE];
#pragma unroll
        for (int q = 0; q < 4; q++)
            *(f32x4*)(al + q * 4) = *(const f32x4*)(A_log + (size_t)d * STATE + q * 4);
#pragma unroll
        for (int s = 0; s < STATE; s++) A[s] = -__expf(al[s]);
    }
    const size_t hidx = ((size_t)(b * NCH + c) * INNER + d) * STATE;
#pragma unroll
    for (int q = 0; q < 4; q++)
        *(f32x4*)(h + q * 4) = *(const f32x4*)(Hc + hidx + q * 4);

    const float Dd = Dv[d];
    const size_t base = (size_t)b * LSEQ + (size_t)c * TC;

#pragma unroll 2
    for (int t = 0; t < TC; t++) {
        const size_t r = base + t;
        const float dtv = bf2f(dt[r * INNER + d]);
        const float xv  = bf2f(xc[r * INNER + d]);
        const float dtx = dtv * xv;
        float Bv[STATE], Cv[STATE];
#pragma unroll
        for (int q = 0; q < 4; q++) {
            *(f32x4*)(Bv + q * 4) = *(const f32x4*)(Bm + r * STATE + q * 4);
            *(f32x4*)(Cv + q * 4) = *(const f32x4*)(Cm + r * STATE + q * 4);
        }
        float y = Dd * xv;
#pragma unroll
        for (int s = 0; s < STATE; s++) {
            const float dA = __expf(dtv * A[s]);
            h[s] = fmaf(dA, h[s], dtx * Bv[s]);
            y = fmaf(h[s], Cv[s], y);
        }
        const float zv = bf2f(sz_y[r * INNER + d]);
        sz_y[r * INNER + d] = f2bf(y * zv);
    }
}

// ---------- launch ----------
extern "C" void kernel_launch(void* const* d_in, const int* in_sizes, int n_in,
                              void* d_out, int out_size, void* d_ws, size_t ws_size,
                              hipStream_t stream) {
    const float* x       = (const float*)d_in[0];
    const float* in_w    = (const float*)d_in[1];
    const float* in_b    = (const float*)d_in[2];
    const float* conv_w  = (const float*)d_in[3];
    const float* conv_b  = (const float*)d_in[4];
    const float* dt_w    = (const float*)d_in[5];
    const float* dt_b    = (const float*)d_in[6];
    const float* A_log   = (const float*)d_in[7];
    const float* B_w     = (const float*)d_in[8];
    const float* B_b     = (const float*)d_in[9];
    const float* C_w     = (const float*)d_in[10];
    const float* C_b     = (const float*)d_in[11];
    const float* Dv      = (const float*)d_in[12];
    const float* out_w   = (const float*)d_in[13];
    const float* out_b   = (const float*)d_in[14];
    float* out = (float*)d_out;

    char* ws = (char*)d_ws;
    size_t off = 0;
    auto alloc = [&](size_t bytes) { size_t o = off; off += (bytes + 255) & ~(size_t)255; return o; };

    ushort_t* Xbf     = (ushort_t*)(ws + alloc((size_t)BL * HID * 2));       // 32 MB   [dead after GEMM1]
    ushort_t* W1bf    = (ushort_t*)(ws + alloc((size_t)2 * INNER * HID * 2));// 8 MB    [dead after GEMM1]
    ushort_t* Wcat    = (ushort_t*)(ws + alloc((size_t)NCAT * INNER * 2));   // 8.5 MB  [dead after GEMM2]
    ushort_t* Woutbf  = (ushort_t*)(ws + alloc((size_t)HID * INNER * 2));    // 4 MB
    float*    biascat = (float*)   (ws + alloc((size_t)NCAT * 4));
    ushort_t* xpart   = (ushort_t*)(ws + alloc((size_t)BL * INNER * 2));     // 64 MB, reused as dt
    ushort_t* szbf    = (ushort_t*)(ws + alloc((size_t)BL * INNER * 2));     // 64 MB, y in-place
    ushort_t* xconvbf = (ushort_t*)(ws + alloc((size_t)BL * INNER * 2));     // 64 MB
    float*    Bmbuf   = (float*)   (ws + alloc((size_t)BL * STATE * 4));     // 1 MB
    float*    Cmbuf   = (float*)   (ws + alloc((size_t)BL * STATE * 4));     // 1 MB
    ushort_t* dtbuf   = xpart;   // x_part dead after conv

    // Chunk-scan scratch overlays the dead Xbf/W1bf/Wcat region (~48.5 MB):
    //   P bf16: 16 MB at ws+0; S fp32: 32 MB after (48 MB total, fits)
    ushort_t* Pbuf = (ushort_t*)ws;
    float*    Sbuf = (float*)(ws + (size_t)NCH * BSZ * INNER * STATE * 2);
    (void)in_sizes; (void)n_in; (void)out_size;

    // If workspace is too small, skip launches: harness reports clean absmax
    // failure (== max|ref|) instead of a device page-fault core dump.
    if (ws_size < off) return;

    // casts / weight packing
    {
        int n = BL * HID;
        cast_bf16_kernel<<<(n + 255) / 256, 256, 0, stream>>>(x, Xbf, n);
        n = 2 * INNER * HID;
        cast_bf16_kernel<<<(n + 255) / 256, 256, 0, stream>>>(in_w, W1bf, n);
        n = HID * INNER;
        cast_bf16_kernel<<<(n + 255) / 256, 256, 0, stream>>>(out_w, Woutbf, n);
        n = NCAT * INNER;
        build_wcat_kernel<<<(n + 255) / 256, 256, 0, stream>>>(dt_w, B_w, C_w, Wcat);
        build_biascat_kernel<<<(NCAT + 255) / 256, 256, 0, stream>>>(dt_b, B_b, C_b, biascat);
    }

    // GEMM1: xz = x @ in_proj_w^T + b  -> x_part bf16, silu(z) bf16
    gemm256_kernel<0, HID><<<dim3((2 * INNER) / 128, BL / 256), 512, 0, stream>>>(
        Xbf, W1bf, in_b, xpart, szbf, nullptr, nullptr, nullptr, 2 * INNER);

    // causal depthwise conv + silu -> x_conv bf16
    conv_silu_kernel<<<(BL * INNER / 8) / 256, 256, 0, stream>>>(xpart, conv_w, conv_b, xconvbf);

    // GEMM2: [dt_pre | Bm | Cm | pad] = x_conv @ Wcat^T + biascat ; softplus fused for dt
    gemm256_kernel<1, INNER><<<dim3(NCAT / 128, BL / 256), 512, 0, stream>>>(
        xconvbf, Wcat, biascat, dtbuf, nullptr, nullptr, Bmbuf, Cmbuf, NCAT);

    // chunked selective scan (+ D*x, * silu(z)) -> y_gated bf16 (in-place over silu(z))
    scan_pass1<<<dim3(INNER / 256, NCH, BSZ), 256, 0, stream>>>(
        dtbuf, xconvbf, Bmbuf, A_log, Pbuf, Sbuf);
    scan_pass2<<<(BSZ * INNER * STATE) / 256, 256, 0, stream>>>(Pbuf, Sbuf);
    scan_pass3<<<dim3(INNER / 256, NCH, BSZ), 256, 0, stream>>>(
        dtbuf, xconvbf, Bmbuf, Cmbuf, A_log, Dv, Sbuf, szbf);

    // GEMM3: out = y_gated @ out_w^T + out_b
    gemm256_kernel<2, INNER><<<dim3(HID / 128, BL / 256), 512, 0, stream>>>(
        szbf, Woutbf, out_b, nullptr, nullptr, out, nullptr, nullptr, HID);
}

// Round 7
// 1019.059 us; speedup vs baseline: 1.0353x; 1.0353x over previous
//
#include <hip/hip_runtime.h>
#include <hip/hip_bf16.h>

// MambaSSMBlock: HID=1024, STATE=16, K=4, EXPAND=2, INNER=2048, B=4, L=4096
#define HID   1024
#define STATE 16
#define KCONV 4
#define INNER 2048
#define BSZ   4
#define LSEQ  4096
#define BL    (BSZ * LSEQ)       // 16384 rows
#define NCAT  2176               // 2048 (dt) + 16 (B) + 16 (C) + 96 pad -> 17 tiles of 128
#define NCH   64                 // scan chunks
#define TC    64                 // steps per chunk (NCH*TC == LSEQ)

typedef unsigned short ushort_t;
typedef unsigned int   uint_t;
typedef __attribute__((ext_vector_type(8))) __bf16 bf16x8;
typedef __attribute__((ext_vector_type(4))) float  f32x4;
typedef __attribute__((ext_vector_type(8))) unsigned short u16x8;

// ---------- helpers ----------
__device__ __forceinline__ ushort_t f2bf(float f) {
    uint_t u = __float_as_uint(f);
    u += 0x7fffu + ((u >> 16) & 1u);       // RNE (finite values only here)
    return (ushort_t)(u >> 16);
}
__device__ __forceinline__ float bf2f(ushort_t h) {
    return __uint_as_float(((uint_t)h) << 16);
}

#define AS1 __attribute__((address_space(1)))
#define AS3 __attribute__((address_space(3)))
__device__ __forceinline__ void async_copy16(const ushort_t* g, ushort_t* l) {
    // LDS dest is wave-uniform base; HW writes lane i at base + i*16B
    __builtin_amdgcn_global_load_lds((const AS1 void*)g, (AS3 void*)l, 16, 0, 0);
}

// ---------- elementwise cast ----------
__global__ void cast_bf16_kernel(const float* __restrict__ src, ushort_t* __restrict__ dst, int n) {
    int i = blockIdx.x * 256 + threadIdx.x;
    if (i < n) dst[i] = f2bf(src[i]);
}

// ---------- build concatenated [dt_w; B_w; C_w; 0-pad] bf16 weight (NCAT x 2048) ----------
__global__ void build_wcat_kernel(const float* __restrict__ dtw, const float* __restrict__ Bw,
                                  const float* __restrict__ Cw, ushort_t* __restrict__ out) {
    int i = blockIdx.x * 256 + threadIdx.x;
    if (i >= NCAT * INNER) return;
    int r = i >> 11;           // / 2048
    int k = i & (INNER - 1);
    float v = 0.f;
    if (r < INNER)            v = dtw[i];
    else if (r < INNER + 16)  v = Bw[(r - INNER) * INNER + k];
    else if (r < INNER + 32)  v = Cw[(r - INNER - 16) * INNER + k];
    out[i] = f2bf(v);
}

__global__ void build_biascat_kernel(const float* __restrict__ dtb, const float* __restrict__ Bb,
                                     const float* __restrict__ Cb, float* __restrict__ out) {
    int i = blockIdx.x * 256 + threadIdx.x;
    if (i >= NCAT) return;
    float v = 0.f;
    if (i < INNER)            v = dtb[i];
    else if (i < INNER + 16)  v = Bb[i - INNER];
    else if (i < INNER + 32)  v = Cb[i - INNER - 16];
    out[i] = v;
}

// ---------- 256x128x64 8-phase bf16 MFMA GEMM: C = A(M,K) @ B(N,K)^T ----------
// 8 waves (2Mx4N), 512 threads, 96KB LDS = 2 bufs x [B(128x64)|A0|A1] x 16KB.
// R7: 4-quadrant schedule (T3+T4+T5) on the R6 tile. R6 (2-phase) measured
// MfmaUtil 22.5% with 1 block/CU: the per-tile stage->vmcnt(0)->barrier drain
// is fully exposed (m233). Quadrants interleave ds_read/stage/MFMA and keep
// B(t+2) in flight ACROSS the tile boundary (vmcnt(2), never 0 mid-loop):
//   q0 {read aF[0..3],b0 | stage A0(t+1)} q1 {read b1 | stage A1(t+1)}
//   q2 {read aF[4..7]    | stage B(t+2) } q3 {held regs only}
// each phase: barrier -> setprio(1) 8 MFMA setprio(0) -> barrier.
// Ring hazards: A-slot stages write the OPPOSITE buffer (last read 4 phases
// prior); B(t+2) writes the current buffer's B slot in q2, after the q1-end
// barrier at which all waves hold b0/b1 in registers. Register peak ~132
// (acc 64 + aF 32 + b 16 + addr) -- no spill (R5's 8-phase spilled at acc=128;
// R6 verified acc=64 fits: VGPR 88, WRITE_SIZE ideal).
// T2 XOR swizzle kept (0 bank conflicts, R3/R6-verified); T1 XCD banding kept.
// MODE 0: in_proj  -> col<2048: x_part bf16; col>=2048: silu(z) bf16
// MODE 1: dt/Bm/Cm -> col<2048: softplus->dt bf16; [2048,2064): Bm; [2064,2080): Cm; pad dropped
// MODE 2: out_proj -> bias add, fp32
#define mfma_bf16 __builtin_amdgcn_mfma_f32_16x16x32_bf16

template <int MODE, int KK>
__global__ __launch_bounds__(512, 2) void gemm256_kernel(
    const ushort_t* __restrict__ A, const ushort_t* __restrict__ Bw,
    const float* __restrict__ bias,
    ushort_t* __restrict__ oU0, ushort_t* __restrict__ oU1,
    float* __restrict__ oF, float* __restrict__ oB, float* __restrict__ oC,
    int N)
{
    __shared__ ushort_t smem[49152];   // 96 KiB: 2 bufs x 3 slots x 8192 ushorts

    const int tid  = threadIdx.x;
    const int w    = tid >> 6;
    const int lane = tid & 63;
    const int m16  = lane & 15;
    const int ko   = lane >> 4;        // 0..3 : which 8-elem k-chunk
    const int wm   = w >> 2;           // 0..1 : row-half of the 256-row tile
    const int wn   = w & 3;            // 0..3 : 32-col quarter of the 128-col tile

    // ----- XCD-banded swizzle (gridDim.y == 64, nwg % 8 == 0 for all shapes) -----
    const int gx   = gridDim.x;
    const int lb   = blockIdx.y * gx + blockIdx.x;
    const int xcd  = lb & 7;
    const int slot = lb >> 3;
    const int tx   = slot % gx;
    const int ty   = xcd * 8 + slot / gx;    // 8 row-tiles per XCD band
    const int row0 = ty * 256;
    const int col0 = tx * 128;

    constexpr int NKT = KK >> 6;       // K-tiles of 64

    // per-lane staging base (swizzle pre-applied to GLOBAL source; LDS dest
    // linear -- rule #21): lane covers row w*16 + i*8 + (lane>>3), chunk
    // c16 = lane&7, src chunk = c16 ^ (row&7) = (lane&7)^(lane>>3).
    const size_t Lofs = (size_t)(w * 16 + (lane >> 3)) * KK
                      + (size_t)(((lane & 7) ^ (lane >> 3)) << 3);
    const ushort_t* pA = A  + (size_t)row0 * KK + Lofs;
    const ushort_t* pB = Bw + (size_t)col0 * KK + Lofs;

    f32x4 acc[8][2] = {};

    // stage one 16KB slot j of K-tile tau into buffer (tau&1):
    // j=0: B rows 0-127; j=1: A rows 0-127; j=2: A rows 128-255.
    auto stage_slot = [&](int j, int tau) {
        const int bb = (tau & 1) * 24576;
        const int k0 = tau << 6;
        const ushort_t* px = (j == 0) ? pB : pA + (size_t)((j - 1) << 7) * KK;
#pragma unroll
        for (int i = 0; i < 2; i++) {
            async_copy16(px + (size_t)(i * 8) * KK + k0,
                         &smem[bb + j * 8192 + w * 1024 + i * 512]);
        }
    };
    // swizzled ds_read of one bf16x8 MFMA fragment (row stride 64 ushorts=128B)
    auto ldA = [&](int buf, int rf, int s) -> bf16x8 {
        const int row = (rf << 4) + m16;                 // within wm's 128-row half
        const int c16 = ((s << 2) + ko) ^ (row & 7);
        return *(const bf16x8*)&smem[buf * 24576 + (1 + wm) * 8192 + (row << 6) + (c16 << 3)];
    };
    auto ldB = [&](int buf, int cf, int s) -> bf16x8 {
        const int row = (wn << 5) + (cf << 4) + m16;     // 0..127
        const int c16 = ((s << 2) + ko) ^ (row & 7);
        return *(const bf16x8*)&smem[buf * 24576 + (row << 6) + (c16 << 3)];
    };

    // prologue: tile0 fully + B(1); wait tile0 resident (B(1) stays in flight)
    stage_slot(0, 0); stage_slot(1, 0); stage_slot(2, 0);
    stage_slot(0, 1);
    asm volatile("s_waitcnt vmcnt(2)" ::: "memory");
    __builtin_amdgcn_s_barrier();

#pragma unroll 1
    for (int t = 0; t < NKT; ++t) {
        const int buf = t & 1;
        bf16x8 aF[4][2], b0[2], b1[2];

        // ---- q0: read aF[0..3]+b0; stage A0(t+1); MFMA acc[0..3][0]
#pragma unroll
        for (int rf = 0; rf < 4; rf++) { aF[rf][0] = ldA(buf, rf, 0); aF[rf][1] = ldA(buf, rf, 1); }
        b0[0] = ldB(buf, 0, 0); b0[1] = ldB(buf, 0, 1);
        if (t + 1 < NKT) stage_slot(1, t + 1);
        __builtin_amdgcn_s_barrier();
        __builtin_amdgcn_s_setprio(1);
#pragma unroll
        for (int rf = 0; rf < 4; rf++) {
            acc[rf][0] = mfma_bf16(aF[rf][0], b0[0], acc[rf][0], 0, 0, 0);
            acc[rf][0] = mfma_bf16(aF[rf][1], b0[1], acc[rf][0], 0, 0, 0);
        }
        __builtin_amdgcn_s_setprio(0);
        __builtin_amdgcn_s_barrier();

        // ---- q1: read b1; stage A1(t+1); MFMA acc[0..3][1]
        b1[0] = ldB(buf, 1, 0); b1[1] = ldB(buf, 1, 1);
        if (t + 1 < NKT) stage_slot(2, t + 1);
        __builtin_amdgcn_s_barrier();
        __builtin_amdgcn_s_setprio(1);
#pragma unroll
        for (int rf = 0; rf < 4; rf++) {
            acc[rf][1] = mfma_bf16(aF[rf][0], b1[0], acc[rf][1], 0, 0, 0);
            acc[rf][1] = mfma_bf16(aF[rf][1], b1[1], acc[rf][1], 0, 0, 0);
        }
        __builtin_amdgcn_s_setprio(0);
        __builtin_amdgcn_s_barrier();

        // ---- q2: read aF[4..7] (reuse regs); stage B(t+2); MFMA acc[4..7][1]
#pragma unroll
        for (int rf = 0; rf < 4; rf++) { aF[rf][0] = ldA(buf, 4 + rf, 0); aF[rf][1] = ldA(buf, 4 + rf, 1); }
        if (t + 2 < NKT) stage_slot(0, t + 2);
        __builtin_amdgcn_s_barrier();
        __builtin_amdgcn_s_setprio(1);
#pragma unroll
        for (int rf = 0; rf < 4; rf++) {
            acc[4 + rf][1] = mfma_bf16(aF[rf][0], b1[0], acc[4 + rf][1], 0, 0, 0);
            acc[4 + rf][1] = mfma_bf16(aF[rf][1], b1[1], acc[4 + rf][1], 0, 0, 0);
        }
        __builtin_amdgcn_s_setprio(0);
        __builtin_amdgcn_s_barrier();

        // ---- q3: held regs only; MFMA acc[4..7][0]; boundary counted vmcnt
        __builtin_amdgcn_s_setprio(1);
#pragma unroll
        for (int rf = 0; rf < 4; rf++) {
            acc[4 + rf][0] = mfma_bf16(aF[rf][0], b0[0], acc[4 + rf][0], 0, 0, 0);
            acc[4 + rf][0] = mfma_bf16(aF[rf][1], b0[1], acc[4 + rf][0], 0, 0, 0);
        }
        __builtin_amdgcn_s_setprio(0);
        if (t + 1 < NKT) {
            if (t + 1 == NKT - 1) asm volatile("s_waitcnt vmcnt(0)" ::: "memory");
            else                  asm volatile("s_waitcnt vmcnt(2)" ::: "memory");
            __builtin_amdgcn_s_barrier();
        }
    }

    // ---------------- epilogue ----------------
    // C/D layout: col = lane&15, row = (lane>>4)*4 + reg
    const int rbase = (lane >> 4) * 4;
    __syncthreads();   // all K-loop LDS reads done before smem reuse; drains cnts

    if (MODE == 2) {
        // fp32 direct: 16 lanes x 4B contiguous = full 64B line per store instr
#pragma unroll
        for (int rf = 0; rf < 8; rf++)
#pragma unroll
            for (int cf = 0; cf < 2; cf++)
#pragma unroll
                for (int r = 0; r < 4; r++) {
                    int row = row0 + wm * 128 + rf * 16 + rbase + r;
                    int col = col0 + wn * 32 + cf * 16 + m16;
                    oF[(size_t)row * N + col] = acc[rf][cf][r] + bias[col];
                }
    } else if (MODE == 1 && col0 >= INNER) {
        // Bm/Cm strip (cols 2048..2079) + pad cols: scalar fp32, tiny
#pragma unroll
        for (int rf = 0; rf < 8; rf++)
#pragma unroll
            for (int cf = 0; cf < 2; cf++)
#pragma unroll
                for (int r = 0; r < 4; r++) {
                    int row = row0 + wm * 128 + rf * 16 + rbase + r;
                    int col = col0 + wn * 32 + cf * 16 + m16;
                    float v = acc[rf][cf][r] + bias[col];
                    if (col < INNER + 16)      oB[(size_t)row * STATE + (col - INNER)] = v;
                    else if (col < INNER + 32) oC[(size_t)row * STATE + (col - INNER - 16)] = v;
                }
    } else {
        // bf16 modes: per-wave-private LDS transpose -> u16x8 full-line stores
        const bool isZ = (MODE == 0) && (col0 >= INNER);   // block-uniform
        ushort_t* my = &smem[w * 4608];                    // 128 rows x 36 ushorts
        const int SW = 36;                                 // padded row stride
#pragma unroll
        for (int rf = 0; rf < 8; rf++)
#pragma unroll
            for (int cf = 0; cf < 2; cf++)
#pragma unroll
                for (int r = 0; r < 4; r++) {
                    int lr = rf * 16 + rbase + r;          // 0..127
                    int lc = cf * 16 + m16;                // 0..31
                    float v = acc[rf][cf][r] + bias[col0 + wn * 32 + lc];
                    ushort_t o;
                    if (MODE == 0) {
                        if (isZ) { float s = v / (1.f + __expf(-v)); o = f2bf(s); }
                        else     { o = f2bf(v); }
                    } else {
                        float sp = fmaxf(v, 0.f) + log1pf(__expf(-fabsf(v)));
                        o = f2bf(sp);
                    }
                    my[lr * SW + lc] = o;
                }
        // same-wave DS ordering (HW in-order per wave); sched_barrier as
        // insurance against compile-time reordering of the read loop
        __builtin_amdgcn_sched_barrier(0);
#pragma unroll
        for (int it = 0; it < 8; it++) {
            int lr = it * 16 + (lane >> 2);                // 0..127
            u16x8 vv = *(const u16x8*)&my[lr * SW + (lane & 3) * 8];
            int grow = row0 + wm * 128 + lr;
            int gcol = col0 + wn * 32 + (lane & 3) * 8;
            if (MODE == 0 && isZ)
                *(u16x8*)&oU1[(size_t)grow * INNER + (gcol - INNER)] = vv;
            else
                *(u16x8*)&oU0[(size_t)grow * INNER + gcol] = vv;
        }
    }
}

// ---------- causal depthwise conv (K=4) + silu; bf16 in, bf16 out ----------
// Vectorized x8 (G13): each thread owns 8 contiguous channels at one (b,l);
// u16x8 loads for the 4 tap rows, conv weights hoisted to registers.
__global__ void conv_silu_kernel(const ushort_t* __restrict__ xp, const float* __restrict__ cw,
                                 const float* __restrict__ cb,
                                 ushort_t* __restrict__ xcbf) {
    int i = blockIdx.x * 256 + threadIdx.x;     // over BL*INNER/8
    int base = i * 8;
    int d0 = base & (INNER - 1);
    int bl = base >> 11;
    int l  = bl & (LSEQ - 1);

    f32x4 wv[8];
    float acc[8];
#pragma unroll
    for (int j = 0; j < 8; j++) {
        wv[j]  = *(const f32x4*)&cw[(d0 + j) * KCONV];
        acc[j] = cb[d0 + j];
    }
#pragma unroll
    for (int k = 0; k < KCONV; k++) {
        int ls = l - (KCONV - 1) + k;
        if (ls >= 0) {
            u16x8 v = *(const u16x8*)&xp[base + (ls - l) * INNER];
#pragma unroll
            for (int j = 0; j < 8; j++) acc[j] = fmaf(wv[j][k], bf2f(v[j]), acc[j]);
        }
    }
    u16x8 o;
#pragma unroll
    for (int j = 0; j < 8; j++) {
        float s = acc[j] / (1.f + __expf(-acc[j]));
        o[j] = f2bf(s);
    }
    *(u16x8*)&xcbf[base] = o;
}

// ---------- chunked parallel scan, thread-per-channel ----------
__global__ __launch_bounds__(256) void scan_pass1(
    const ushort_t* __restrict__ dt, const ushort_t* __restrict__ xc,
    const float* __restrict__ Bm, const float* __restrict__ A_log,
    ushort_t* __restrict__ Pc, float* __restrict__ Sc)
{
    const int b = blockIdx.z;
    const int c = blockIdx.y;
    const int d = blockIdx.x * 256 + threadIdx.x;

    float A[STATE], h[STATE];
    {
        float al[STATE];
#pragma unroll
        for (int q = 0; q < 4; q++)
            *(f32x4*)(al + q * 4) = *(const f32x4*)(A_log + (size_t)d * STATE + q * 4);
#pragma unroll
        for (int s = 0; s < STATE; s++) { A[s] = -__expf(al[s]); h[s] = 0.f; }
    }
    float sdt = 0.f;
    const size_t base = (size_t)b * LSEQ + (size_t)c * TC;

#pragma unroll 2
    for (int t = 0; t < TC; t++) {
        const size_t r = base + t;
        const float dtv = bf2f(dt[r * INNER + d]);
        const float xv  = bf2f(xc[r * INNER + d]);
        const float dtx = dtv * xv;
        float Bv[STATE];
#pragma unroll
        for (int q = 0; q < 4; q++)
            *(f32x4*)(Bv + q * 4) = *(const f32x4*)(Bm + r * STATE + q * 4);
        sdt += dtv;
#pragma unroll
        for (int s = 0; s < STATE; s++) {
            const float dA = __expf(dtv * A[s]);
            h[s] = fmaf(dA, h[s], dtx * Bv[s]);
        }
    }

    const size_t idx = ((size_t)(b * NCH + c) * INNER + d) * STATE;
#pragma unroll
    for (int q = 0; q < 4; q++)
        *(f32x4*)(Sc + idx + q * 4) = *(const f32x4*)(h + q * 4);
    u16x8 p0, p1;
#pragma unroll
    for (int s = 0; s < 8; s++) { p0[s] = f2bf(__expf(A[s] * sdt)); }
#pragma unroll
    for (int s = 0; s < 8; s++) { p1[s] = f2bf(__expf(A[s + 8] * sdt)); }
    *(u16x8*)(Pc + idx)     = p0;
    *(u16x8*)(Pc + idx + 8) = p1;
}

// Pass 2: exclusive scan over chunks (in-place: S becomes H = chunk-initial state).
__global__ __launch_bounds__(256) void scan_pass2(
    const ushort_t* __restrict__ Pc, float* Sc)
{
    const int i = blockIdx.x * 256 + threadIdx.x;      // over BSZ*INNER*STATE
    const int b   = i >> 15;                           // / (INNER*STATE)
    const int rem = i & (INNER * STATE - 1);
    float H = 0.f;
#pragma unroll 8
    for (int c = 0; c < NCH; c++) {
        const size_t idx = (size_t)(b * NCH + c) * (INNER * STATE) + rem;
        const float Pv = bf2f(Pc[idx]);
        const float Sv = Sc[idx];
        const float Hn = fmaf(Pv, H, Sv);
        Sc[idx] = H;                                   // exclusive: h at chunk start
        H = Hn;
    }
}

// Pass 3: re-run local scan seeded with H; y = sum_s h[s]*C[s] + D*x; gate with
// silu(z) in-place. No shuffles: states are registers.
__global__ __launch_bounds__(256) void scan_pass3(
    const ushort_t* __restrict__ dt, const ushort_t* __restrict__ xc,
    const float* __restrict__ Bm, const float* __restrict__ Cm,
    const float* __restrict__ A_log, const float* __restrict__ Dv,
    const float* __restrict__ Hc, ushort_t* sz_y)
{
    const int b = blockIdx.z;
    const int c = blockIdx.y;
    const int d = blockIdx.x * 256 + threadIdx.x;

    float A[STATE], h[STATE];
    {
        float al[STATE];
#pragma unroll
        for (int q = 0; q < 4; q++)
            *(f32x4*)(al + q * 4) = *(const f32x4*)(A_log + (size_t)d * STATE + q * 4);
#pragma unroll
        for (int s = 0; s < STATE; s++) A[s] = -__expf(al[s]);
    }
    const size_t hidx = ((size_t)(b * NCH + c) * INNER + d) * STATE;
#pragma unroll
    for (int q = 0; q < 4; q++)
        *(f32x4*)(h + q * 4) = *(const f32x4*)(Hc + hidx + q * 4);

    const float Dd = Dv[d];
    const size_t base = (size_t)b * LSEQ + (size_t)c * TC;

#pragma unroll 2
    for (int t = 0; t < TC; t++) {
        const size_t r = base + t;
        const float dtv = bf2f(dt[r * INNER + d]);
        const float xv  = bf2f(xc[r * INNER + d]);
        const float dtx = dtv * xv;
        float Bv[STATE], Cv[STATE];
#pragma unroll
        for (int q = 0; q < 4; q++) {
            *(f32x4*)(Bv + q * 4) = *(const f32x4*)(Bm + r * STATE + q * 4);
            *(f32x4*)(Cv + q * 4) = *(const f32x4*)(Cm + r * STATE + q * 4);
        }
        float y = Dd * xv;
#pragma unroll
        for (int s = 0; s < STATE; s++) {
            const float dA = __expf(dtv * A[s]);
            h[s] = fmaf(dA, h[s], dtx * Bv[s]);
            y = fmaf(h[s], Cv[s], y);
        }
        const float zv = bf2f(sz_y[r * INNER + d]);
        sz_y[r * INNER + d] = f2bf(y * zv);
    }
}

// ---------- launch ----------
extern "C" void kernel_launch(void* const* d_in, const int* in_sizes, int n_in,
                              void* d_out, int out_size, void* d_ws, size_t ws_size,
                              hipStream_t stream) {
    const float* x       = (const float*)d_in[0];
    const float* in_w    = (const float*)d_in[1];
    const float* in_b    = (const float*)d_in[2];
    const float* conv_w  = (const float*)d_in[3];
    const float* conv_b  = (const float*)d_in[4];
    const float* dt_w    = (const float*)d_in[5];
    const float* dt_b    = (const float*)d_in[6];
    const float* A_log   = (const float*)d_in[7];
    const float* B_w     = (const float*)d_in[8];
    const float* B_b     = (const float*)d_in[9];
    const float* C_w     = (const float*)d_in[10];
    const float* C_b     = (const float*)d_in[11];
    const float* Dv      = (const float*)d_in[12];
    const float* out_w   = (const float*)d_in[13];
    const float* out_b   = (const float*)d_in[14];
    float* out = (float*)d_out;

    char* ws = (char*)d_ws;
    size_t off = 0;
    auto alloc = [&](size_t bytes) { size_t o = off; off += (bytes + 255) & ~(size_t)255; return o; };

    ushort_t* Xbf     = (ushort_t*)(ws + alloc((size_t)BL * HID * 2));       // 32 MB   [dead after GEMM1]
    ushort_t* W1bf    = (ushort_t*)(ws + alloc((size_t)2 * INNER * HID * 2));// 8 MB    [dead after GEMM1]
    ushort_t* Wcat    = (ushort_t*)(ws + alloc((size_t)NCAT * INNER * 2));   // 8.5 MB  [dead after GEMM2]
    ushort_t* Woutbf  = (ushort_t*)(ws + alloc((size_t)HID * INNER * 2));    // 4 MB
    float*    biascat = (float*)   (ws + alloc((size_t)NCAT * 4));
    ushort_t* xpart   = (ushort_t*)(ws + alloc((size_t)BL * INNER * 2));     // 64 MB, reused as dt
    ushort_t* szbf    = (ushort_t*)(ws + alloc((size_t)BL * INNER * 2));     // 64 MB, y in-place
    ushort_t* xconvbf = (ushort_t*)(ws + alloc((size_t)BL * INNER * 2));     // 64 MB
    float*    Bmbuf   = (float*)   (ws + alloc((size_t)BL * STATE * 4));     // 1 MB
    float*    Cmbuf   = (float*)   (ws + alloc((size_t)BL * STATE * 4));     // 1 MB
    ushort_t* dtbuf   = xpart;   // x_part dead after conv

    // Chunk-scan scratch overlays the dead Xbf/W1bf/Wcat region (~48.5 MB):
    //   P bf16: 16 MB at ws+0; S fp32: 32 MB after (48 MB total, fits)
    ushort_t* Pbuf = (ushort_t*)ws;
    float*    Sbuf = (float*)(ws + (size_t)NCH * BSZ * INNER * STATE * 2);
    (void)in_sizes; (void)n_in; (void)out_size;

    // If workspace is too small, skip launches: harness reports clean absmax
    // failure (== max|ref|) instead of a device page-fault core dump.
    if (ws_size < off) return;

    // casts / weight packing
    {
        int n = BL * HID;
        cast_bf16_kernel<<<(n + 255) / 256, 256, 0, stream>>>(x, Xbf, n);
        n = 2 * INNER * HID;
        cast_bf16_kernel<<<(n + 255) / 256, 256, 0, stream>>>(in_w, W1bf, n);
        n = HID * INNER;
        cast_bf16_kernel<<<(n + 255) / 256, 256, 0, stream>>>(out_w, Woutbf, n);
        n = NCAT * INNER;
        build_wcat_kernel<<<(n + 255) / 256, 256, 0, stream>>>(dt_w, B_w, C_w, Wcat);
        build_biascat_kernel<<<(NCAT + 255) / 256, 256, 0, stream>>>(dt_b, B_b, C_b, biascat);
    }

    // GEMM1: xz = x @ in_proj_w^T + b  -> x_part bf16, silu(z) bf16
    gemm256_kernel<0, HID><<<dim3((2 * INNER) / 128, BL / 256), 512, 0, stream>>>(
        Xbf, W1bf, in_b, xpart, szbf, nullptr, nullptr, nullptr, 2 * INNER);

    // causal depthwise conv + silu -> x_conv bf16
    conv_silu_kernel<<<(BL * INNER / 8) / 256, 256, 0, stream>>>(xpart, conv_w, conv_b, xconvbf);

    // GEMM2: [dt_pre | Bm | Cm | pad] = x_conv @ Wcat^T + biascat ; softplus fused for dt
    gemm256_kernel<1, INNER><<<dim3(NCAT / 128, BL / 256), 512, 0, stream>>>(
        xconvbf, Wcat, biascat, dtbuf, nullptr, nullptr, Bmbuf, Cmbuf, NCAT);

    // chunked selective scan (+ D*x, * silu(z)) -> y_gated bf16 (in-place over silu(z))
    scan_pass1<<<dim3(INNER / 256, NCH, BSZ), 256, 0, stream>>>(
        dtbuf, xconvbf, Bmbuf, A_log, Pbuf, Sbuf);
    scan_pass2<<<(BSZ * INNER * STATE) / 256, 256, 0, stream>>>(Pbuf, Sbuf);
    scan_pass3<<<dim3(INNER / 256, NCH, BSZ), 256, 0, stream>>>(
        dtbuf, xconvbf, Bmbuf, Cmbuf, A_log, Dv, Sbuf, szbf);

    // GEMM3: out = y_gated @ out_w^T + out_b
    gemm256_kernel<2, INNER><<<dim3(HID / 128, BL / 256), 512, 0, stream>>>(
        szbf, Woutbf, out_b, nullptr, nullptr, out, nullptr, nullptr, HID);
}

// Round 8
// 925.742 us; speedup vs baseline: 1.1397x; 1.1008x over previous
//
#include <hip/hip_runtime.h>
#include <hip/hip_bf16.h>

// MambaSSMBlock: HID=1024, STATE=16, K=4, EXPAND=2, INNER=2048, B=4, L=4096
#define HID   1024
#define STATE 16
#define KCONV 4
#define INNER 2048
#define BSZ   4
#define LSEQ  4096
#define BL    (BSZ * LSEQ)       // 16384 rows
#define NCAT  2176               // 2048 (dt) + 16 (B) + 16 (C) + 96 pad -> 17 tiles of 128
#define NCH   64                 // scan chunks
#define TC    64                 // steps per chunk (NCH*TC == LSEQ)

typedef unsigned short ushort_t;
typedef unsigned int   uint_t;
typedef __attribute__((ext_vector_type(8))) __bf16 bf16x8;
typedef __attribute__((ext_vector_type(4))) float  f32x4;
typedef __attribute__((ext_vector_type(8))) unsigned short u16x8;

// ---------- helpers ----------
__device__ __forceinline__ ushort_t f2bf(float f) {
    uint_t u = __float_as_uint(f);
    u += 0x7fffu + ((u >> 16) & 1u);       // RNE (finite values only here)
    return (ushort_t)(u >> 16);
}
__device__ __forceinline__ float bf2f(ushort_t h) {
    return __uint_as_float(((uint_t)h) << 16);
}

#define AS1 __attribute__((address_space(1)))
#define AS3 __attribute__((address_space(3)))
__device__ __forceinline__ void async_copy16(const ushort_t* g, ushort_t* l) {
    // LDS dest is wave-uniform base; HW writes lane i at base + i*16B
    __builtin_amdgcn_global_load_lds((const AS1 void*)g, (AS3 void*)l, 16, 0, 0);
}

// ---------- elementwise cast ----------
__global__ void cast_bf16_kernel(const float* __restrict__ src, ushort_t* __restrict__ dst, int n) {
    int i = blockIdx.x * 256 + threadIdx.x;
    if (i < n) dst[i] = f2bf(src[i]);
}

// ---------- build concatenated [dt_w; B_w; C_w; 0-pad] bf16 weight (NCAT x 2048) ----------
__global__ void build_wcat_kernel(const float* __restrict__ dtw, const float* __restrict__ Bw,
                                  const float* __restrict__ Cw, ushort_t* __restrict__ out) {
    int i = blockIdx.x * 256 + threadIdx.x;
    if (i >= NCAT * INNER) return;
    int r = i >> 11;           // / 2048
    int k = i & (INNER - 1);
    float v = 0.f;
    if (r < INNER)            v = dtw[i];
    else if (r < INNER + 16)  v = Bw[(r - INNER) * INNER + k];
    else if (r < INNER + 32)  v = Cw[(r - INNER - 16) * INNER + k];
    out[i] = f2bf(v);
}

__global__ void build_biascat_kernel(const float* __restrict__ dtb, const float* __restrict__ Bb,
                                     const float* __restrict__ Cb, float* __restrict__ out) {
    int i = blockIdx.x * 256 + threadIdx.x;
    if (i >= NCAT) return;
    float v = 0.f;
    if (i < INNER)            v = dtb[i];
    else if (i < INNER + 16)  v = Bb[i - INNER];
    else if (i < INNER + 32)  v = Cb[i - INNER - 16];
    out[i] = v;
}

// ---------- 256x128x64 bf16 MFMA GEMM, 2 blocks/CU: C = A(M,K) @ B(N,K)^T ----------
// R8: occupancy over pipelining. R6 (dbuf 96KB) and R7 (8-phase) both sat at
// 1 block/CU, 21-22% MfmaUtil: the per-tile stage->drain->barrier is exposed
// because no co-resident block fills it. m114/m97: at >=2 blocks/CU, implicit
// wave-level overlap captures what source pipelining would add (m97: single-
// buffered 2-barrier loop at 3 blocks/CU -> 36% MfmaUtil). So: SINGLE 48KB
// buffer (fits 2 blocks: 2x48=96KB<=160; VGPR 88 -> 4 waves/SIMD = 16 waves),
// loop {barrier; stage(t); vmcnt(0); barrier; compute(t)} -- drain of one
// block overlaps compute of the sibling.
// T2 XOR swizzle kept (0 bank conflicts, R3/R6-verified); T1 XCD banding kept.
// acc[8][2]=64 f32/lane, no spill (R6-verified: VGPR 88, WRITE ideal).
// Epilogue: per-wave LDS transpose in TWO 64-row passes (36KB peak <= 48KB).
// MODE 0: in_proj  -> col<2048: x_part bf16; col>=2048: silu(z) bf16
// MODE 1: dt/Bm/Cm -> col<2048: softplus->dt bf16; [2048,2064): Bm; [2064,2080): Cm; pad dropped
// MODE 2: out_proj -> bias add, fp32
#define mfma_bf16 __builtin_amdgcn_mfma_f32_16x16x32_bf16

template <int MODE, int KK>
__global__ __launch_bounds__(512, 4) void gemm256_kernel(
    const ushort_t* __restrict__ A, const ushort_t* __restrict__ Bw,
    const float* __restrict__ bias,
    ushort_t* __restrict__ oU0, ushort_t* __restrict__ oU1,
    float* __restrict__ oF, float* __restrict__ oB, float* __restrict__ oC,
    int N)
{
    __shared__ ushort_t smem[24576];   // 48 KiB: [B(128x64)|A0|A1] x 8192 ushorts

    const int tid  = threadIdx.x;
    const int w    = tid >> 6;
    const int lane = tid & 63;
    const int m16  = lane & 15;
    const int ko   = lane >> 4;        // 0..3 : which 8-elem k-chunk
    const int wm   = w >> 2;           // 0..1 : row-half of the 256-row tile
    const int wn   = w & 3;            // 0..3 : 32-col quarter of the 128-col tile

    // ----- XCD-banded swizzle (gridDim.y == 64, nwg % 8 == 0 for all shapes) -----
    const int gx   = gridDim.x;
    const int lb   = blockIdx.y * gx + blockIdx.x;
    const int xcd  = lb & 7;
    const int slot = lb >> 3;
    const int tx   = slot % gx;
    const int ty   = xcd * 8 + slot / gx;    // 8 row-tiles per XCD band
    const int row0 = ty * 256;
    const int col0 = tx * 128;

    constexpr int NKT = KK >> 6;       // K-tiles of 64

    // per-lane staging base (swizzle pre-applied to GLOBAL source; LDS dest
    // linear -- rule #21): lane covers row w*16 + i*8 + (lane>>3), chunk
    // c16 = lane&7, src chunk = c16 ^ (row&7) = (lane&7)^(lane>>3).
    const size_t Lofs = (size_t)(w * 16 + (lane >> 3)) * KK
                      + (size_t)(((lane & 7) ^ (lane >> 3)) << 3);
    const ushort_t* pA = A  + (size_t)row0 * KK + Lofs;
    const ushort_t* pB = Bw + (size_t)col0 * KK + Lofs;

    f32x4 acc[8][2] = {};

    // stage K-tile tau into the single buffer: slots j=0:B(128r), j=1:A rows
    // 0-127, j=2:A rows 128-255. 6 global_load_lds per wave.
    auto stage_tile = [&](int tau) {
        const int k0 = tau << 6;
#pragma unroll
        for (int j = 0; j < 3; j++) {
            const ushort_t* px = (j == 0) ? pB : pA + (size_t)((j - 1) << 7) * KK;
#pragma unroll
            for (int i = 0; i < 2; i++) {
                async_copy16(px + (size_t)(i * 8) * KK + k0,
                             &smem[j * 8192 + w * 1024 + i * 512]);
            }
        }
    };
    // swizzled ds_read of one bf16x8 MFMA fragment (row stride 64 ushorts=128B)
    auto ldA = [&](int rf, int s) -> bf16x8 {
        const int row = (rf << 4) + m16;                 // within wm's 128-row half
        const int c16 = ((s << 2) + ko) ^ (row & 7);
        return *(const bf16x8*)&smem[(1 + wm) * 8192 + (row << 6) + (c16 << 3)];
    };
    auto ldB = [&](int cf, int s) -> bf16x8 {
        const int row = (wn << 5) + (cf << 4) + m16;     // 0..127
        const int c16 = ((s << 2) + ko) ^ (row & 7);
        return *(const bf16x8*)&smem[(row << 6) + (c16 << 3)];
    };

#pragma unroll 1
    for (int t = 0; t < NKT; ++t) {
        if (t) __builtin_amdgcn_s_barrier();     // prior tile's reads complete
        stage_tile(t);
        asm volatile("s_waitcnt vmcnt(0)" ::: "memory");   // own DMA landed
        __builtin_amdgcn_s_barrier();                      // all waves' DMA landed

#pragma unroll
        for (int s = 0; s < 2; s++) {
            const bf16x8 b0 = ldB(0, s);
            const bf16x8 b1 = ldB(1, s);
#pragma unroll
            for (int rf = 0; rf < 8; rf++) {
                const bf16x8 a = ldA(rf, s);
                acc[rf][0] = mfma_bf16(a, b0, acc[rf][0], 0, 0, 0);
                acc[rf][1] = mfma_bf16(a, b1, acc[rf][1], 0, 0, 0);
            }
        }
    }

    // ---------------- epilogue ----------------
    // C/D layout: col = lane&15, row = (lane>>4)*4 + reg
    const int rbase = (lane >> 4) * 4;
    __syncthreads();   // all K-loop LDS reads done before smem reuse; drains cnts

    if (MODE == 2) {
        // fp32 direct: 16 lanes x 4B contiguous = full 64B line per store instr
#pragma unroll
        for (int rf = 0; rf < 8; rf++)
#pragma unroll
            for (int cf = 0; cf < 2; cf++)
#pragma unroll
                for (int r = 0; r < 4; r++) {
                    int row = row0 + wm * 128 + rf * 16 + rbase + r;
                    int col = col0 + wn * 32 + cf * 16 + m16;
                    oF[(size_t)row * N + col] = acc[rf][cf][r] + bias[col];
                }
    } else if (MODE == 1 && col0 >= INNER) {
        // Bm/Cm strip (cols 2048..2079) + pad cols: scalar fp32, tiny
#pragma unroll
        for (int rf = 0; rf < 8; rf++)
#pragma unroll
            for (int cf = 0; cf < 2; cf++)
#pragma unroll
                for (int r = 0; r < 4; r++) {
                    int row = row0 + wm * 128 + rf * 16 + rbase + r;
                    int col = col0 + wn * 32 + cf * 16 + m16;
                    float v = acc[rf][cf][r] + bias[col];
                    if (col < INNER + 16)      oB[(size_t)row * STATE + (col - INNER)] = v;
                    else if (col < INNER + 32) oC[(size_t)row * STATE + (col - INNER - 16)] = v;
                }
    } else {
        // bf16 modes: per-wave-private LDS transpose -> u16x8 full-line stores.
        // Two 64-row passes: 8 waves x 64 x 36 ushorts = 36KB <= 48KB.
        const bool isZ = (MODE == 0) && (col0 >= INNER);   // block-uniform
        ushort_t* my = &smem[w * 2304];                    // 64 rows x 36 ushorts
        const int SW = 36;                                 // padded row stride
#pragma unroll
        for (int p = 0; p < 2; p++) {
#pragma unroll
            for (int rf4 = 0; rf4 < 4; rf4++)
#pragma unroll
                for (int cf = 0; cf < 2; cf++)
#pragma unroll
                    for (int r = 0; r < 4; r++) {
                        int lr = rf4 * 16 + rbase + r;     // 0..63
                        int lc = cf * 16 + m16;            // 0..31
                        float v = acc[p * 4 + rf4][cf][r] + bias[col0 + wn * 32 + lc];
                        ushort_t o;
                        if (MODE == 0) {
                            if (isZ) { float s = v / (1.f + __expf(-v)); o = f2bf(s); }
                            else     { o = f2bf(v); }
                        } else {
                            float sp = fmaxf(v, 0.f) + log1pf(__expf(-fabsf(v)));
                            o = f2bf(sp);
                        }
                        my[lr * SW + lc] = o;
                    }
            // same-wave DS ordering (HW in-order per wave); sched_barrier as
            // insurance against compile-time reordering across the passes
            __builtin_amdgcn_sched_barrier(0);
#pragma unroll
            for (int it = 0; it < 4; it++) {
                int lr = it * 16 + (lane >> 2);            // 0..63
                u16x8 vv = *(const u16x8*)&my[lr * SW + (lane & 3) * 8];
                int grow = row0 + wm * 128 + p * 64 + lr;
                int gcol = col0 + wn * 32 + (lane & 3) * 8;
                if (MODE == 0 && isZ)
                    *(u16x8*)&oU1[(size_t)grow * INNER + (gcol - INNER)] = vv;
                else
                    *(u16x8*)&oU0[(size_t)grow * INNER + gcol] = vv;
            }
            __builtin_amdgcn_sched_barrier(0);
        }
    }
}

// ---------- causal depthwise conv (K=4) + silu; bf16 in, bf16 out ----------
// Vectorized x8 (G13): each thread owns 8 contiguous channels at one (b,l);
// u16x8 loads for the 4 tap rows, conv weights hoisted to registers.
__global__ void conv_silu_kernel(const ushort_t* __restrict__ xp, const float* __restrict__ cw,
                                 const float* __restrict__ cb,
                                 ushort_t* __restrict__ xcbf) {
    int i = blockIdx.x * 256 + threadIdx.x;     // over BL*INNER/8
    int base = i * 8;
    int d0 = base & (INNER - 1);
    int bl = base >> 11;
    int l  = bl & (LSEQ - 1);

    f32x4 wv[8];
    float acc[8];
#pragma unroll
    for (int j = 0; j < 8; j++) {
        wv[j]  = *(const f32x4*)&cw[(d0 + j) * KCONV];
        acc[j] = cb[d0 + j];
    }
#pragma unroll
    for (int k = 0; k < KCONV; k++) {
        int ls = l - (KCONV - 1) + k;
        if (ls >= 0) {
            u16x8 v = *(const u16x8*)&xp[base + (ls - l) * INNER];
#pragma unroll
            for (int j = 0; j < 8; j++) acc[j] = fmaf(wv[j][k], bf2f(v[j]), acc[j]);
        }
    }
    u16x8 o;
#pragma unroll
    for (int j = 0; j < 8; j++) {
        float s = acc[j] / (1.f + __expf(-acc[j]));
        o[j] = f2bf(s);
    }
    *(u16x8*)&xcbf[base] = o;
}

// ---------- chunked parallel scan, thread-per-channel ----------
__global__ __launch_bounds__(256) void scan_pass1(
    const ushort_t* __restrict__ dt, const ushort_t* __restrict__ xc,
    const float* __restrict__ Bm, const float* __restrict__ A_log,
    ushort_t* __restrict__ Pc, float* __restrict__ Sc)
{
    const int b = blockIdx.z;
    const int c = blockIdx.y;
    const int d = blockIdx.x * 256 + threadIdx.x;

    float A[STATE], h[STATE];
    {
        float al[STATE];
#pragma unroll
        for (int q = 0; q < 4; q++)
            *(f32x4*)(al + q * 4) = *(const f32x4*)(A_log + (size_t)d * STATE + q * 4);
#pragma unroll
        for (int s = 0; s < STATE; s++) { A[s] = -__expf(al[s]); h[s] = 0.f; }
    }
    float sdt = 0.f;
    const size_t base = (size_t)b * LSEQ + (size_t)c * TC;

#pragma unroll 2
    for (int t = 0; t < TC; t++) {
        const size_t r = base + t;
        const float dtv = bf2f(dt[r * INNER + d]);
        const float xv  = bf2f(xc[r * INNER + d]);
        const float dtx = dtv * xv;
        float Bv[STATE];
#pragma unroll
        for (int q = 0; q < 4; q++)
            *(f32x4*)(Bv + q * 4) = *(const f32x4*)(Bm + r * STATE + q * 4);
        sdt += dtv;
#pragma unroll
        for (int s = 0; s < STATE; s++) {
            const float dA = __expf(dtv * A[s]);
            h[s] = fmaf(dA, h[s], dtx * Bv[s]);
        }
    }

    const size_t idx = ((size_t)(b * NCH + c) * INNER + d) * STATE;
#pragma unroll
    for (int q = 0; q < 4; q++)
        *(f32x4*)(Sc + idx + q * 4) = *(const f32x4*)(h + q * 4);
    u16x8 p0, p1;
#pragma unroll
    for (int s = 0; s < 8; s++) { p0[s] = f2bf(__expf(A[s] * sdt)); }
#pragma unroll
    for (int s = 0; s < 8; s++) { p1[s] = f2bf(__expf(A[s + 8] * sdt)); }
    *(u16x8*)(Pc + idx)     = p0;
    *(u16x8*)(Pc + idx + 8) = p1;
}

// Pass 2: exclusive scan over chunks (in-place: S becomes H = chunk-initial state).
__global__ __launch_bounds__(256) void scan_pass2(
    const ushort_t* __restrict__ Pc, float* Sc)
{
    const int i = blockIdx.x * 256 + threadIdx.x;      // over BSZ*INNER*STATE
    const int b   = i >> 15;                           // / (INNER*STATE)
    const int rem = i & (INNER * STATE - 1);
    float H = 0.f;
#pragma unroll 8
    for (int c = 0; c < NCH; c++) {
        const size_t idx = (size_t)(b * NCH + c) * (INNER * STATE) + rem;
        const float Pv = bf2f(Pc[idx]);
        const float Sv = Sc[idx];
        const float Hn = fmaf(Pv, H, Sv);
        Sc[idx] = H;                                   // exclusive: h at chunk start
        H = Hn;
    }
}

// Pass 3: re-run local scan seeded with H; y = sum_s h[s]*C[s] + D*x; gate with
// silu(z) in-place. No shuffles: states are registers.
__global__ __launch_bounds__(256) void scan_pass3(
    const ushort_t* __restrict__ dt, const ushort_t* __restrict__ xc,
    const float* __restrict__ Bm, const float* __restrict__ Cm,
    const float* __restrict__ A_log, const float* __restrict__ Dv,
    const float* __restrict__ Hc, ushort_t* sz_y)
{
    const int b = blockIdx.z;
    const int c = blockIdx.y;
    const int d = blockIdx.x * 256 + threadIdx.x;

    float A[STATE], h[STATE];
    {
        float al[STATE];
#pragma unroll
        for (int q = 0; q < 4; q++)
            *(f32x4*)(al + q * 4) = *(const f32x4*)(A_log + (size_t)d * STATE + q * 4);
#pragma unroll
        for (int s = 0; s < STATE; s++) A[s] = -__expf(al[s]);
    }
    const size_t hidx = ((size_t)(b * NCH + c) * INNER + d) * STATE;
#pragma unroll
    for (int q = 0; q < 4; q++)
        *(f32x4*)(h + q * 4) = *(const f32x4*)(Hc + hidx + q * 4);

    const float Dd = Dv[d];
    const size_t base = (size_t)b * LSEQ + (size_t)c * TC;

#pragma unroll 2
    for (int t = 0; t < TC; t++) {
        const size_t r = base + t;
        const float dtv = bf2f(dt[r * INNER + d]);
        const float xv  = bf2f(xc[r * INNER + d]);
        const float dtx = dtv * xv;
        float Bv[STATE], Cv[STATE];
#pragma unroll
        for (int q = 0; q < 4; q++) {
            *(f32x4*)(Bv + q * 4) = *(const f32x4*)(Bm + r * STATE + q * 4);
            *(f32x4*)(Cv + q * 4) = *(const f32x4*)(Cm + r * STATE + q * 4);
        }
        float y = Dd * xv;
#pragma unroll
        for (int s = 0; s < STATE; s++) {
            const float dA = __expf(dtv * A[s]);
            h[s] = fmaf(dA, h[s], dtx * Bv[s]);
            y = fmaf(h[s], Cv[s], y);
        }
        const float zv = bf2f(sz_y[r * INNER + d]);
        sz_y[r * INNER + d] = f2bf(y * zv);
    }
}

// ---------- launch ----------
extern "C" void kernel_launch(void* const* d_in, const int* in_sizes, int n_in,
                              void* d_out, int out_size, void* d_ws, size_t ws_size,
                              hipStream_t stream) {
    const float* x       = (const float*)d_in[0];
    const float* in_w    = (const float*)d_in[1];
    const float* in_b    = (const float*)d_in[2];
    const float* conv_w  = (const float*)d_in[3];
    const float* conv_b  = (const float*)d_in[4];
    const float* dt_w    = (const float*)d_in[5];
    const float* dt_b    = (const float*)d_in[6];
    const float* A_log   = (const float*)d_in[7];
    const float* B_w     = (const float*)d_in[8];
    const float* B_b     = (const float*)d_in[9];
    const float* C_w     = (const float*)d_in[10];
    const float* C_b     = (const float*)d_in[11];
    const float* Dv      = (const float*)d_in[12];
    const float* out_w   = (const float*)d_in[13];
    const float* out_b   = (const float*)d_in[14];
    float* out = (float*)d_out;

    char* ws = (char*)d_ws;
    size_t off = 0;
    auto alloc = [&](size_t bytes) { size_t o = off; off += (bytes + 255) & ~(size_t)255; return o; };

    ushort_t* Xbf     = (ushort_t*)(ws + alloc((size_t)BL * HID * 2));       // 32 MB   [dead after GEMM1]
    ushort_t* W1bf    = (ushort_t*)(ws + alloc((size_t)2 * INNER * HID * 2));// 8 MB    [dead after GEMM1]
    ushort_t* Wcat    = (ushort_t*)(ws + alloc((size_t)NCAT * INNER * 2));   // 8.5 MB  [dead after GEMM2]
    ushort_t* Woutbf  = (ushort_t*)(ws + alloc((size_t)HID * INNER * 2));    // 4 MB
    float*    biascat = (float*)   (ws + alloc((size_t)NCAT * 4));
    ushort_t* xpart   = (ushort_t*)(ws + alloc((size_t)BL * INNER * 2));     // 64 MB, reused as dt
    ushort_t* szbf    = (ushort_t*)(ws + alloc((size_t)BL * INNER * 2));     // 64 MB, y in-place
    ushort_t* xconvbf = (ushort_t*)(ws + alloc((size_t)BL * INNER * 2));     // 64 MB
    float*    Bmbuf   = (float*)   (ws + alloc((size_t)BL * STATE * 4));     // 1 MB
    float*    Cmbuf   = (float*)   (ws + alloc((size_t)BL * STATE * 4));     // 1 MB
    ushort_t* dtbuf   = xpart;   // x_part dead after conv

    // Chunk-scan scratch overlays the dead Xbf/W1bf/Wcat region (~48.5 MB):
    //   P bf16: 16 MB at ws+0; S fp32: 32 MB after (48 MB total, fits)
    ushort_t* Pbuf = (ushort_t*)ws;
    float*    Sbuf = (float*)(ws + (size_t)NCH * BSZ * INNER * STATE * 2);
    (void)in_sizes; (void)n_in; (void)out_size;

    // If workspace is too small, skip launches: harness reports clean absmax
    // failure (== max|ref|) instead of a device page-fault core dump.
    if (ws_size < off) return;

    // casts / weight packing
    {
        int n = BL * HID;
        cast_bf16_kernel<<<(n + 255) / 256, 256, 0, stream>>>(x, Xbf, n);
        n = 2 * INNER * HID;
        cast_bf16_kernel<<<(n + 255) / 256, 256, 0, stream>>>(in_w, W1bf, n);
        n = HID * INNER;
        cast_bf16_kernel<<<(n + 255) / 256, 256, 0, stream>>>(out_w, Woutbf, n);
        n = NCAT * INNER;
        build_wcat_kernel<<<(n + 255) / 256, 256, 0, stream>>>(dt_w, B_w, C_w, Wcat);
        build_biascat_kernel<<<(NCAT + 255) / 256, 256, 0, stream>>>(dt_b, B_b, C_b, biascat);
    }

    // GEMM1: xz = x @ in_proj_w^T + b  -> x_part bf16, silu(z) bf16
    gemm256_kernel<0, HID><<<dim3((2 * INNER) / 128, BL / 256), 512, 0, stream>>>(
        Xbf, W1bf, in_b, xpart, szbf, nullptr, nullptr, nullptr, 2 * INNER);

    // causal depthwise conv + silu -> x_conv bf16
    conv_silu_kernel<<<(BL * INNER / 8) / 256, 256, 0, stream>>>(xpart, conv_w, conv_b, xconvbf);

    // GEMM2: [dt_pre | Bm | Cm | pad] = x_conv @ Wcat^T + biascat ; softplus fused for dt
    gemm256_kernel<1, INNER><<<dim3(NCAT / 128, BL / 256), 512, 0, stream>>>(
        xconvbf, Wcat, biascat, dtbuf, nullptr, nullptr, Bmbuf, Cmbuf, NCAT);

    // chunked selective scan (+ D*x, * silu(z)) -> y_gated bf16 (in-place over silu(z))
    scan_pass1<<<dim3(INNER / 256, NCH, BSZ), 256, 0, stream>>>(
        dtbuf, xconvbf, Bmbuf, A_log, Pbuf, Sbuf);
    scan_pass2<<<(BSZ * INNER * STATE) / 256, 256, 0, stream>>>(Pbuf, Sbuf);
    scan_pass3<<<dim3(INNER / 256, NCH, BSZ), 256, 0, stream>>>(
        dtbuf, xconvbf, Bmbuf, Cmbuf, A_log, Dv, Sbuf, szbf);

    // GEMM3: out = y_gated @ out_w^T + out_b
    gemm256_kernel<2, INNER><<<dim3(HID / 128, BL / 256), 512, 0, stream>>>(
        szbf, Woutbf, out_b, nullptr, nullptr, out, nullptr, nullptr, HID);
}